// Round 1
// baseline (552.031 us; speedup 1.0000x reference)
//
#include <hip/hip_runtime.h>
#include <cstddef>
#include <cstdint>

// ---------------- problem constants ----------------
#define ALPHA_C 7.7550531393693407f   // -log(0.001/7*3)
constexpr int BB = 2;      // batch
constexpr int LL = 2048;   // seq len
constexpr int HH = 8;      // heads
constexpr size_t OUT0  = (size_t)BB * LL * 512;          // output 0 floats
constexpr size_t PLANE = (size_t)BB * HH * LL * 64;      // per-head-major plane elems
constexpr size_t XN    = (size_t)BB * LL * 512;          // X plane elems (4096x512)
constexpr size_t WN    = (size_t)512 * 512;              // W plane elems
constexpr size_t UGN   = (size_t)BB * HH * LL * LL;      // u buffer elems (16*2048*2048)

typedef __attribute__((ext_vector_type(8))) short bf16x8;
typedef __attribute__((ext_vector_type(4))) short short4v;
typedef __attribute__((ext_vector_type(4))) float f32x4;

__device__ inline short f2bf(float x) {
  union { float f; unsigned u; } un; un.f = x;
  unsigned r = un.u + 0x7fffu + ((un.u >> 16) & 1u);   // RNE
  return (short)(r >> 16);
}
__device__ inline float bf2f(short s) {
  union { unsigned u; float f; } un; un.u = ((unsigned)(unsigned short)s) << 16;
  return un.f;
}
// 3-way bf16 split: x ~= h + m + l (~24 mantissa bits)
__device__ inline void split3(float x, short& h, short& m, short& l) {
  h = f2bf(x); float r = x - bf2f(h);
  m = f2bf(r); float r2 = r - bf2f(m);
  l = f2bf(r2);
}

// ---------------- K0: elementwise split3 into bf16 planes (x3 tensors) --------
__global__ __launch_bounds__(256) void k_split3x(
    const float* __restrict__ a, const float* __restrict__ b, const float* __restrict__ c,
    short* __restrict__ da, short* __restrict__ db, short* __restrict__ dc, size_t n)
{
  size_t i = ((size_t)blockIdx.x * 256 + threadIdx.x) * 4;
  if (i >= n) return;
  const float* srcs[3] = {a, b, c};
  short* dsts[3] = {da, db, dc};
  #pragma unroll
  for (int s = 0; s < 3; ++s) {
    float4 x = *(const float4*)&srcs[s][i];
    short4v h, m, l;
    short th, tm, tl;
    split3(x.x, th, tm, tl); h[0] = th; m[0] = tm; l[0] = tl;
    split3(x.y, th, tm, tl); h[1] = th; m[1] = tm; l[1] = tl;
    split3(x.z, th, tm, tl); h[2] = th; m[2] = tm; l[2] = tl;
    split3(x.w, th, tm, tl); h[3] = th; m[3] = tm; l[3] = tl;
    *(short4v*)&dsts[s][i]         = h;
    *(short4v*)&dsts[s][n + i]     = m;
    *(short4v*)&dsts[s][2 * n + i] = l;
  }
}

// ---------------- K0c: fp32 -> bf16 convert (w_fc) ----------------
__global__ __launch_bounds__(256) void k_cvtbf(
    const float* __restrict__ src, short* __restrict__ dst, size_t n)
{
  size_t i = ((size_t)blockIdx.x * 256 + threadIdx.x) * 8;
  if (i >= n) return;
  float4 a = *(const float4*)&src[i];
  float4 b = *(const float4*)&src[i + 4];
  bf16x8 o;
  o[0] = f2bf(a.x); o[1] = f2bf(a.y); o[2] = f2bf(a.z); o[3] = f2bf(a.w);
  o[4] = f2bf(b.x); o[5] = f2bf(b.y); o[6] = f2bf(b.z); o[7] = f2bf(b.w);
  *(bf16x8*)&dst[i] = o;
}

// ---------------- K0b: 3-tap avg-pool of V^T along l (zero-padded) ----------------
__global__ __launch_bounds__(256) void k_vavg(
    const short* __restrict__ vt, short* __restrict__ vavgt)
{
  const size_t row = blockIdx.x;           // 1024 rows of LL
  const short* src = vt + row * LL;
  short* dst = vavgt + row * LL;
  const int c0 = threadIdx.x * 8;
  bf16x8 x = *(const bf16x8*)&src[c0];
  float xf[10];
  xf[0] = (c0 > 0) ? bf2f(src[c0 - 1]) : 0.f;
  #pragma unroll
  for (int i = 0; i < 8; ++i) xf[i + 1] = bf2f(x[i]);
  xf[9] = (c0 + 8 < LL) ? bf2f(src[c0 + 8]) : 0.f;
  bf16x8 o;
  #pragma unroll
  for (int i = 0; i < 8; ++i) o[i] = f2bf((xf[i] + xf[i + 1] + xf[i + 2]) * (1.0f / 3.0f));
  *(bf16x8*)&dst[c0] = o;
}

// ---------------- K1: QKV projection — 6-term split bf16 MFMA ----------------
__global__ __launch_bounds__(256) void k_proj(
    const short* __restrict__ xq, const short* __restrict__ xk, const short* __restrict__ xv,
    const short* __restrict__ wq3, const short* __restrict__ wk3, const short* __restrict__ wv3,
    short* __restrict__ qs, short* __restrict__ ks, short* __restrict__ vt)
{
  const int bx  = blockIdx.x;
  const int sel = bx >> 3;
  const int n0  = (bx & 7) * 64;
  const int m0  = blockIdx.y * 64;
  const short* X = sel == 0 ? xq  : (sel == 1 ? xk  : xv);
  const short* W = sel == 0 ? wq3 : (sel == 1 ? wk3 : wv3);

  __shared__ short Xs[3][64 * 72];
  __shared__ short Ws[3][64 * 72];
  const int tid = threadIdx.x;
  const int lane = tid & 63, w = tid >> 6;
  const int quad = lane >> 4, l15 = lane & 15, colg = l15;
  const int sr8 = tid >> 3, sc8 = (tid & 7) * 8;

  f32x4 acc[4];
  #pragma unroll
  for (int t = 0; t < 4; ++t) { acc[t][0]=0.f; acc[t][1]=0.f; acc[t][2]=0.f; acc[t][3]=0.f; }

  for (int kt = 0; kt < 8; ++kt) {
    const int k0 = kt * 64;
    #pragma unroll
    for (int p = 0; p < 3; ++p) {
      #pragma unroll
      for (int it = 0; it < 2; ++it) {
        int r = it * 32 + sr8;
        *(bf16x8*)&Xs[p][r * 72 + sc8] = *(const bf16x8*)&X[p * XN + (size_t)(m0 + r) * 512 + k0 + sc8];
        *(bf16x8*)&Ws[p][r * 72 + sc8] = *(const bf16x8*)&W[p * WN + (size_t)(n0 + r) * 512 + k0 + sc8];
      }
    }
    __syncthreads();
    #pragma unroll
    for (int ch = 0; ch < 2; ++ch) {
      const int ka = (quad << 3) + ch * 32;
      const int ar = (w * 16 + l15) * 72 + ka;
      bf16x8 ah = *(const bf16x8*)&Xs[0][ar];
      bf16x8 am = *(const bf16x8*)&Xs[1][ar];
      bf16x8 al = *(const bf16x8*)&Xs[2][ar];
      #pragma unroll
      for (int t = 0; t < 4; ++t) {
        const int br = (t * 16 + l15) * 72 + ka;
        bf16x8 bh_ = *(const bf16x8*)&Ws[0][br];
        bf16x8 bm_ = *(const bf16x8*)&Ws[1][br];
        bf16x8 bl_ = *(const bf16x8*)&Ws[2][br];
        acc[t] = __builtin_amdgcn_mfma_f32_16x16x32_bf16(ah, bh_, acc[t], 0, 0, 0);
        acc[t] = __builtin_amdgcn_mfma_f32_16x16x32_bf16(ah, bm_, acc[t], 0, 0, 0);
        acc[t] = __builtin_amdgcn_mfma_f32_16x16x32_bf16(am, bh_, acc[t], 0, 0, 0);
        acc[t] = __builtin_amdgcn_mfma_f32_16x16x32_bf16(ah, bl_, acc[t], 0, 0, 0);
        acc[t] = __builtin_amdgcn_mfma_f32_16x16x32_bf16(al, bh_, acc[t], 0, 0, 0);
        acc[t] = __builtin_amdgcn_mfma_f32_16x16x32_bf16(am, bm_, acc[t], 0, 0, 0);
      }
    }
    __syncthreads();
  }

  if (sel < 2) {
    short* Y = sel == 0 ? qs : ks;
    #pragma unroll
    for (int t = 0; t < 4; ++t) {
      const int e = n0 + t * 16 + colg, h = e >> 6, dk = e & 63;
      #pragma unroll
      for (int r = 0; r < 4; ++r) {
        const int m = m0 + w * 16 + quad * 4 + r;
        const int b = m >> 11, l = m & 2047;
        size_t base = ((size_t)(b * HH + h) * LL + l) * 64 + dk;
        short hh, mm, ll; split3(acc[t][r], hh, mm, ll);
        Y[base] = hh; Y[PLANE + base] = mm; Y[2 * PLANE + base] = ll;
      }
    }
  } else {
    const int b  = m0 >> 11;
    const int l0 = (m0 & 2047) + w * 16 + quad * 4;
    #pragma unroll
    for (int t = 0; t < 4; ++t) {
      const int e = n0 + t * 16 + colg, h = e >> 6, dk = e & 63;
      short4v s;
      #pragma unroll
      for (int r = 0; r < 4; ++r) s[r] = f2bf(acc[t][r]);
      *(short4v*)&vt[(((size_t)b * HH + h) * 64 + dk) * LL + l0] = s;
    }
  }
}

// ---------------- K2 (pass A): flash stats + u-spill, j-split x2 ----------------
// Computes partial (M,S) AND writes u = exp(e - M_run) (bf16) to ug, plus
// per-(row,tile) running max mtile so pass B can reconstruct p = u*exp(mt-M)/S.
// Tile max made row-uniform via 4x shfl_xor over the 16 colg lanes.
__global__ __launch_bounds__(256) void k_stats_u(
    const short* __restrict__ qs, const short* __restrict__ ks,
    float* __restrict__ statspart, short* __restrict__ ug,
    float* __restrict__ mtile)
{
  const int i0 = blockIdx.x * 64;
  const int jh = blockIdx.y;           // 0/1: j-tiles [jh*16, jh*16+16)
  const int bh = blockIdx.z;
  __shared__ short Ks[3][64 * 72];
  __shared__ short Us[64 * 72];        // u staging for coalesced global write
  const int tid = threadIdx.x;
  const int lane = tid & 63, w = tid >> 6;
  const int quad = lane >> 4, colg = lane & 15, l15 = lane & 15;
  const int sr8 = tid >> 3, sc8 = (tid & 7) * 8;

  bf16x8 qf[3][2];
  {
    const size_t qoff = ((size_t)bh * LL + i0 + w * 16 + l15) * 64 + (quad << 3);
    #pragma unroll
    for (int p = 0; p < 3; ++p)
      #pragma unroll
      for (int ch = 0; ch < 2; ++ch)
        qf[p][ch] = *(const bf16x8*)&qs[p * PLANE + qoff + ch * 32];
  }

  const int jt0 = jh * 16;
  const short* kbase = ks + (size_t)bh * LL * 64;
  #pragma unroll
  for (int p = 0; p < 3; ++p)
    #pragma unroll
    for (int it = 0; it < 2; ++it) {
      int r = it * 32 + sr8;
      *(bf16x8*)&Ks[p][r * 72 + sc8] =
          *(const bf16x8*)&kbase[p * PLANE + ((size_t)jt0 * 64 + r) * 64 + sc8];
    }
  __syncthreads();

  float M[4], S[4];
  #pragma unroll
  for (int r = 0; r < 4; ++r) { M[r] = -3.0e38f; S[r] = 0.f; }

  for (int jj = 0; jj < 16; ++jj) {
    const int jt = jt0 + jj;
    const int j0 = jt * 64;
    bf16x8 kreg[3][2];
    if (jj + 1 < 16) {
      #pragma unroll
      for (int p = 0; p < 3; ++p)
        #pragma unroll
        for (int it = 0; it < 2; ++it) {
          int r = it * 32 + sr8;
          kreg[p][it] = *(const bf16x8*)&kbase[p * PLANE + ((size_t)(jt + 1) * 64 + r) * 64 + sc8];
        }
    }

    f32x4 acc[4];
    #pragma unroll
    for (int t = 0; t < 4; ++t) { acc[t][0]=0.f; acc[t][1]=0.f; acc[t][2]=0.f; acc[t][3]=0.f; }
    #pragma unroll
    for (int ch = 0; ch < 2; ++ch) {
      const int ka = (quad << 3) + ch * 32;
      #pragma unroll
      for (int t = 0; t < 4; ++t) {
        const int br = (t * 16 + l15) * 72 + ka;
        bf16x8 bh_ = *(const bf16x8*)&Ks[0][br];
        bf16x8 bm_ = *(const bf16x8*)&Ks[1][br];
        bf16x8 bl_ = *(const bf16x8*)&Ks[2][br];
        acc[t] = __builtin_amdgcn_mfma_f32_16x16x32_bf16(qf[0][ch], bh_, acc[t], 0, 0, 0);
        acc[t] = __builtin_amdgcn_mfma_f32_16x16x32_bf16(qf[0][ch], bm_, acc[t], 0, 0, 0);
        acc[t] = __builtin_amdgcn_mfma_f32_16x16x32_bf16(qf[1][ch], bh_, acc[t], 0, 0, 0);
        acc[t] = __builtin_amdgcn_mfma_f32_16x16x32_bf16(qf[0][ch], bl_, acc[t], 0, 0, 0);
        acc[t] = __builtin_amdgcn_mfma_f32_16x16x32_bf16(qf[2][ch], bh_, acc[t], 0, 0, 0);
        acc[t] = __builtin_amdgcn_mfma_f32_16x16x32_bf16(qf[1][ch], bm_, acc[t], 0, 0, 0);
      }
    }

    // row-uniform online update + u scatter to LDS
    float mrow[4];
    #pragma unroll
    for (int r = 0; r < 4; ++r) {
      const int row = w * 16 + quad * 4 + r;
      const int irow = i0 + row;
      float e0 = -ALPHA_C * (float)(j0 +  0 + colg - irow) * (acc[0][r] * 0.125f);
      float e1 = -ALPHA_C * (float)(j0 + 16 + colg - irow) * (acc[1][r] * 0.125f);
      float e2 = -ALPHA_C * (float)(j0 + 32 + colg - irow) * (acc[2][r] * 0.125f);
      float e3 = -ALPHA_C * (float)(j0 + 48 + colg - irow) * (acc[3][r] * 0.125f);
      float mx = fmaxf(fmaxf(e0, e1), fmaxf(e2, e3));
      #pragma unroll
      for (int d = 1; d < 16; d <<= 1) mx = fmaxf(mx, __shfl_xor(mx, d));
      float nM = fmaxf(M[r], mx);
      float u0 = __expf(e0 - nM), u1 = __expf(e1 - nM);
      float u2 = __expf(e2 - nM), u3 = __expf(e3 - nM);
      S[r] = S[r] * __expf(M[r] - nM) + ((u0 + u1) + (u2 + u3));
      M[r] = nM;
      mrow[r] = nM;
      Us[row * 72 +      colg] = f2bf(u0);
      Us[row * 72 + 16 + colg] = f2bf(u1);
      Us[row * 72 + 32 + colg] = f2bf(u2);
      Us[row * 72 + 48 + colg] = f2bf(u3);
    }
    if (colg == 0) {
      f32x4 mm; mm[0] = mrow[0]; mm[1] = mrow[1]; mm[2] = mrow[2]; mm[3] = mrow[3];
      *(f32x4*)&mtile[((size_t)(bh * 32 + jt)) * LL + i0 + w * 16 + quad * 4] = mm;
    }

    __syncthreads();
    // coalesced u write-out + K restage
    #pragma unroll
    for (int it = 0; it < 2; ++it) {
      int r = it * 32 + sr8;
      *(bf16x8*)&ug[((size_t)bh * LL + i0 + r) * LL + j0 + sc8] = *(const bf16x8*)&Us[r * 72 + sc8];
    }
    if (jj + 1 < 16) {
      #pragma unroll
      for (int p = 0; p < 3; ++p)
        #pragma unroll
        for (int it = 0; it < 2; ++it) {
          int r = it * 32 + sr8;
          *(bf16x8*)&Ks[p][r * 72 + sc8] = kreg[p][it];
        }
    }
    __syncthreads();
  }

  // cross-lane merge (16 colg lanes) — M is uniform so this reduces to S-sum,
  // kept in full form for robustness
  #pragma unroll
  for (int r = 0; r < 4; ++r) {
    float M_ = M[r], S_ = S[r];
    #pragma unroll
    for (int d = 1; d < 16; d <<= 1) {
      float Mo = __shfl_xor(M_, d);
      float So = __shfl_xor(S_, d);
      float nM = fmaxf(M_, Mo);
      S_ = S_ * __expf(M_ - nM) + So * __expf(Mo - nM);
      M_ = nM;
    }
    if (colg == 0) {
      int irow = i0 + w * 16 + quad * 4 + r;
      size_t idx = (((size_t)jh * 16 + bh) * LL + irow) * 2;
      statspart[idx] = M_; statspart[idx + 1] = S_;
    }
  }
}

// ---------------- K2b: merge the two j-half partials -> rowstats ----------------
__global__ __launch_bounds__(256) void k_mergestats(
    const float* __restrict__ statspart, float* __restrict__ rowstats)
{
  const size_t row = (size_t)blockIdx.x * 256 + threadIdx.x;   // bh*LL + irow, < 32768
  float2 a = *(const float2*)&statspart[row * 2];
  float2 b = *(const float2*)&statspart[(size_t)16 * LL * 2 + row * 2];
  float nM = fmaxf(a.x, b.x);
  float S = a.y * __expf(a.x - nM) + b.y * __expf(b.x - nM);
  rowstats[row * 2] = nM; rowstats[row * 2 + 1] = S;
}

// ---------------- K3 (pass B): u -> p -> {pool write, PV partial} --------------
// No QK recompute: p = u * exp(mtile - Mfin) * invS. grid (32 i, 16 bh, 2 jz).
// Memory-bound streamer: u read 134MB + pooled write 268MB. 2 barriers/iter.
__global__ __launch_bounds__(256) void k_pv_pool(
    const short* __restrict__ ug, const float* __restrict__ mtile,
    const short* __restrict__ vavgt, const float* __restrict__ rowstats,
    float* __restrict__ pooled, float* __restrict__ pvpart)
{
  const int i0 = blockIdx.x * 64;
  const int bh = blockIdx.y;
  const int jz = blockIdx.z;           // j-tile half: [jz*16, jz*16+16)
  float*       Pg = pooled + (size_t)bh * LL * LL;
  const short* Vt = vavgt + (size_t)bh * 64 * LL;
  const short* Ub = ug + (size_t)bh * LL * LL;

  __shared__ float Pf[64 * 72];        // 18.4 KB f32 p (pool path)
  __shared__ short Pb[64 * 72];        // 9.2 KB bf16 p (PV A-operand)
  __shared__ short Vsm[64 * 72];       // 9.2 KB
  __shared__ float Mrow[64], invSr[64], lhalo[64];

  const int tid = threadIdx.x;
  const int lane = tid & 63, w = tid >> 6;
  const int quad = lane >> 4, colg = lane & 15, l15 = lane & 15;
  const int r8 = tid >> 3, c8 = (tid & 7) * 8;

  if (tid < 64) {
    float2 ms = *(const float2*)&rowstats[((size_t)bh * LL + i0 + tid) * 2];
    Mrow[tid] = ms.x; invSr[tid] = 1.0f / ms.y;
    float lh = 0.f;
    if (jz > 0) {   // left halo = last col of tile jz*16-1, scale-corrected
      float mt = mtile[((size_t)(bh * 32 + jz * 16 - 1)) * LL + i0 + tid];
      lh = bf2f(Ub[(size_t)(i0 + tid) * LL + jz * 16 * 64 - 1]) * __expf(mt - ms.x) * (1.0f / ms.y);
    }
    lhalo[tid] = lh;
  }
  __syncthreads();

  f32x4 pv[4];
  #pragma unroll
  for (int t = 0; t < 4; ++t) { pv[t][0]=0.f; pv[t][1]=0.f; pv[t][2]=0.f; pv[t][3]=0.f; }

  for (int jt = jz * 16; jt < jz * 16 + 16; ++jt) {
    const int j0 = jt * 64;
    // ---- phase A: load u tile, rescale to p, write Pf/Pb; stage V ----
    #pragma unroll
    for (int uu = 0; uu < 2; ++uu) {
      const int row = r8 + uu * 32;
      bf16x8 x = *(const bf16x8*)&Ub[(size_t)(i0 + row) * LL + j0 + c8];
      float mt = mtile[((size_t)(bh * 32 + jt)) * LL + i0 + row];
      float sc = __expf(mt - Mrow[row]) * invSr[row];
      f32x4 p0, p1; bf16x8 pb;
      #pragma unroll
      for (int i = 0; i < 4; ++i) {
        float v0 = bf2f(x[i]) * sc;
        float v1 = bf2f(x[i + 4]) * sc;
        p0[i] = v0; p1[i] = v1;
        pb[i] = f2bf(v0); pb[i + 4] = f2bf(v1);
      }
      *(f32x4*)&Pf[row * 72 + c8]     = p0;
      *(f32x4*)&Pf[row * 72 + c8 + 4] = p1;
      *(bf16x8*)&Pb[row * 72 + c8]    = pb;
    }
    #pragma unroll
    for (int it = 0; it < 2; ++it) {
      int d = it * 32 + r8;
      *(bf16x8*)&Vsm[d * 72 + c8] = *(const bf16x8*)&Vt[(size_t)d * LL + j0 + c8];
    }
    __syncthreads();

    // ---- phase B: pool + pooled write; PV MFMA ----
    #pragma unroll
    for (int uu = 0; uu < 2; ++uu) {
      const int row = r8 + uu * 32;
      const int irow = i0 + row;
      f32x4 a0 = *(const f32x4*)&Pf[row * 72 + c8];
      f32x4 a1 = *(const f32x4*)&Pf[row * 72 + c8 + 4];
      float xf[8];
      xf[0]=a0[0]; xf[1]=a0[1]; xf[2]=a0[2]; xf[3]=a0[3];
      xf[4]=a1[0]; xf[5]=a1[1]; xf[6]=a1[2]; xf[7]=a1[3];
      float lft, rgt;
      lft = (c8 == 0) ? lhalo[row] : Pf[row * 72 + c8 - 1];
      if (c8 == 56) {
        if (jt + 1 < 32) {   // right halo from next tile's first u column
          float mt2 = mtile[((size_t)(bh * 32 + jt + 1)) * LL + irow];
          float sc2 = __expf(mt2 - Mrow[row]) * invSr[row];
          rgt = bf2f(Ub[(size_t)irow * LL + j0 + 64]) * sc2;
        } else rgt = 0.f;
      } else rgt = Pf[row * 72 + c8 + 8];
      f32x4 o0, o1;
      o0[0] = (lft   + xf[0] + xf[1]) * (1.0f/3.0f);
      o0[1] = (xf[0] + xf[1] + xf[2]) * (1.0f/3.0f);
      o0[2] = (xf[1] + xf[2] + xf[3]) * (1.0f/3.0f);
      o0[3] = (xf[2] + xf[3] + xf[4]) * (1.0f/3.0f);
      o1[0] = (xf[3] + xf[4] + xf[5]) * (1.0f/3.0f);
      o1[1] = (xf[4] + xf[5] + xf[6]) * (1.0f/3.0f);
      o1[2] = (xf[5] + xf[6] + xf[7]) * (1.0f/3.0f);
      o1[3] = (xf[6] + xf[7] + rgt  ) * (1.0f/3.0f);
      float* dst = &Pg[(size_t)irow * LL + j0 + c8];
      __builtin_nontemporal_store(o0, (f32x4*)dst);
      __builtin_nontemporal_store(o1, (f32x4*)(dst + 4));
      if (c8 == 56) lhalo[row] = xf[7];
    }
    #pragma unroll
    for (int ch = 0; ch < 2; ++ch) {
      const int ka = (quad << 3) + ch * 32;
      bf16x8 af = *(const bf16x8*)&Pb[(w * 16 + l15) * 72 + ka];
      #pragma unroll
      for (int t = 0; t < 4; ++t) {
        bf16x8 bfv = *(const bf16x8*)&Vsm[(t * 16 + l15) * 72 + ka];
        pv[t] = __builtin_amdgcn_mfma_f32_16x16x32_bf16(af, bfv, pv[t], 0, 0, 0);
      }
    }
    __syncthreads();
  }

  // pv partial out (f32), merged by k_pvmerge
  #pragma unroll
  for (int t = 0; t < 4; ++t)
    #pragma unroll
    for (int r = 0; r < 4; ++r) {
      int i = i0 + w * 16 + quad * 4 + r;
      int d = t * 16 + colg;
      pvpart[(((size_t)(jz * 16 + bh)) * LL + i) * 64 + d] = pv[t][r];
    }
}

// ---------------- K3b: merge pv j-half partials -> outh (bf16) ----------------
__global__ __launch_bounds__(256) void k_pvmerge(
    const float* __restrict__ pvpart, short* __restrict__ outh)
{
  const size_t idx = ((size_t)blockIdx.x * 256 + threadIdx.x) * 4;  // over 16*LL*64
  f32x4 a = *(const f32x4*)&pvpart[idx];
  f32x4 b = *(const f32x4*)&pvpart[(size_t)16 * LL * 64 + idx];
  const int bh = (int)(idx >> 17);           // / (2048*64)
  const int rem = (int)(idx & 131071);
  const int i = rem >> 6, d = rem & 63;
  const int bb = bh >> 3, h = bh & 7;
  short4v o;
  #pragma unroll
  for (int t = 0; t < 4; ++t) o[t] = f2bf(a[t] + b[t]);
  *(short4v*)&outh[((size_t)bb * LL + i) * 512 + h * 64 + d] = o;
}

// ---------------- K4: fc = out_h @ w_fc^T  (pure bf16 MFMA, copy staging) ----------
__global__ __launch_bounds__(256) void k_fc(
    const short* __restrict__ outh, const short* __restrict__ wfcb, float* __restrict__ fcout)
{
  const int n0 = blockIdx.x * 64;
  const int m0 = blockIdx.y * 64;
  __shared__ short Asm[64 * 72];
  __shared__ short Bsm[64 * 72];
  const int tid = threadIdx.x;
  const int lane = tid & 63, w = tid >> 6;
  const int sr8 = tid >> 3, sc8 = (tid & 7) * 8;

  f32x4 acc[4];
  #pragma unroll
  for (int t = 0; t < 4; ++t) { acc[t][0]=0.f; acc[t][1]=0.f; acc[t][2]=0.f; acc[t][3]=0.f; }

  for (int k0 = 0; k0 < 512; k0 += 64) {
    #pragma unroll
    for (int it = 0; it < 2; ++it) {
      int r = it * 32 + sr8;
      *(bf16x8*)&Asm[r * 72 + sc8] = *(const bf16x8*)&outh[(size_t)(m0 + r) * 512 + k0 + sc8];
      *(bf16x8*)&Bsm[r * 72 + sc8] = *(const bf16x8*)&wfcb[(size_t)(n0 + r) * 512 + k0 + sc8];
    }
    __syncthreads();
    #pragma unroll
    for (int ch = 0; ch < 2; ++ch) {
      const int ka = ((lane >> 4) << 3) + ch * 32;
      bf16x8 af = *(const bf16x8*)&Asm[(w * 16 + (lane & 15)) * 72 + ka];
      #pragma unroll
      for (int t = 0; t < 4; ++t) {
        bf16x8 bfv = *(const bf16x8*)&Bsm[(t * 16 + (lane & 15)) * 72 + ka];
        acc[t] = __builtin_amdgcn_mfma_f32_16x16x32_bf16(af, bfv, acc[t], 0, 0, 0);
      }
    }
    __syncthreads();
  }
  const int q4 = lane >> 4, colg = lane & 15;
  #pragma unroll
  for (int t = 0; t < 4; ++t)
    #pragma unroll
    for (int r = 0; r < 4; ++r) {
      int m = m0 + w * 16 + q4 * 4 + r;
      fcout[(size_t)m * 512 + n0 + t * 16 + colg] = acc[t][r];
    }
}

// ---------------- K5: residual + LayerNorm ----------------
__global__ __launch_bounds__(256) void k_ln(
    const float* __restrict__ fcout, const float* __restrict__ resid,
    const float* __restrict__ gamma, const float* __restrict__ beta,
    float* __restrict__ out)
{
  const size_t row = blockIdx.x;
  const int tid = threadIdx.x;
  __shared__ float red[256];

  float x0 = fcout[row * 512 + tid]       + resid[row * 512 + tid];
  float x1 = fcout[row * 512 + 256 + tid] + resid[row * 512 + 256 + tid];

  red[tid] = x0 + x1; __syncthreads();
  for (int off = 128; off > 0; off >>= 1) {
    if (tid < off) red[tid] += red[tid + off];
    __syncthreads();
  }
  const float mu = red[0] * (1.0f / 512.0f); __syncthreads();

  float d0 = x0 - mu, d1 = x1 - mu;
  red[tid] = d0 * d0 + d1 * d1; __syncthreads();
  for (int off = 128; off > 0; off >>= 1) {
    if (tid < off) red[tid] += red[tid + off];
    __syncthreads();
  }
  const float var = red[0] * (1.0f / 512.0f);
  const float rstd = 1.0f / sqrtf(var + 1e-6f);

  out[row * 512 + tid]       = d0 * rstd * gamma[tid]       + beta[tid];
  out[row * 512 + 256 + tid] = d1 * rstd * gamma[tid + 256] + beta[tid + 256];
}

// ---------------- launch ----------------
extern "C" void kernel_launch(void* const* d_in, const int* in_sizes, int n_in,
                              void* d_out, int out_size, void* d_ws, size_t ws_size,
                              hipStream_t stream)
{
  const float* q     = (const float*)d_in[0];
  const float* k     = (const float*)d_in[1];
  const float* v     = (const float*)d_in[2];
  const float* wq    = (const float*)d_in[3];
  const float* wk    = (const float*)d_in[4];
  const float* wv    = (const float*)d_in[5];
  const float* wfc   = (const float*)d_in[6];
  const float* gamma = (const float*)d_in[7];
  const float* beta  = (const float*)d_in[8];

  float* out    = (float*)d_out;
  float* pooled = out + OUT0;

  // workspace layout (~199 MB total):
  // region A [0, UGN shorts): holds the x/w split planes early (dead after
  // k_proj), then the u buffer (written by k_stats_u), then fcout (after
  // k_pv_pool). Persistent buffers follow region A.
  short* ws_s  = (short*)d_ws;
  short* xq    = ws_s;                   // 3*XN   (dead after k_proj)
  short* xk    = xq + 3 * XN;
  short* xv    = xk + 3 * XN;
  short* wq3   = xv + 3 * XN;            // 3*WN each (dead after k_proj)
  short* wk3   = wq3 + 3 * WN;
  short* wv3   = wk3 + 3 * WN;           // early end = 9*XN+9*WN = 21.2M shorts < UGN
  short* ug    = ws_s;                   // UGN shorts (134 MB), aliases the above
  short* qsp   = ug + UGN;               // 3*PLANE
  short* ksp   = qsp + 3 * PLANE;        // 3*PLANE
  short* vt    = ksp + 3 * PLANE;        // PLANE (raw V^T)
  short* vavgt = vt + PLANE;             // PLANE (pooled V^T)
  short* wfcb  = vavgt + PLANE;          // WN bf16
  short* outh  = wfcb + WN;              // OUT0 bf16
  float* statspart = (float*)(outh + OUT0);              // 2 x 32768 x 2 f32
  float* rowstats  = statspart + 4 * (size_t)BB * HH * LL;
  float* mtile     = rowstats + 2 * (size_t)BB * HH * LL; // 16*32*LL f32 (4 MB)
  float* pvpart    = mtile + (size_t)16 * 32 * LL;        // 2*16*LL*64 f32 (16.8 MB)
  float* fcout     = (float*)d_ws;       // aliases ug (dead after k_pv_pool)

  k_split3x<<<dim3((unsigned)(XN / 4 / 256)), 256, 0, stream>>>(q, k, v, xq, xk, xv, XN);
  k_split3x<<<dim3((unsigned)(WN / 4 / 256)), 256, 0, stream>>>(wq, wk, wv, wq3, wk3, wv3, WN);
  k_cvtbf  <<<dim3((unsigned)(WN / 8 / 256)), 256, 0, stream>>>(wfc, wfcb, WN);
  k_proj   <<<dim3(24, 64), 256, 0, stream>>>(xq, xk, xv, wq3, wk3, wv3, qsp, ksp, vt);
  k_vavg   <<<dim3(1024),   256, 0, stream>>>(vt, vavgt);
  k_stats_u<<<dim3(32, 2, 16), 256, 0, stream>>>(qsp, ksp, statspart, ug, mtile);
  k_mergestats<<<dim3(128), 256, 0, stream>>>(statspart, rowstats);
  k_pv_pool<<<dim3(32, 16, 2), 256, 0, stream>>>(ug, mtile, vavgt, rowstats, pooled, pvpart);
  k_pvmerge<<<dim3(2048),   256, 0, stream>>>(pvpart, outh);
  k_fc     <<<dim3(8, 64),  256, 0, stream>>>(outh, wfcb, fcout);
  k_ln     <<<dim3(4096),   256, 0, stream>>>(fcout, q, gamma, beta, out);
}